// Round 1
// baseline (392.114 us; speedup 1.0000x reference)
//
#include <hip/hip_runtime.h>

#define BLK 256

// One thread per element. 32 consecutive lanes = one e8m0 scale block.
// Weights (8 per element, 268 MB total, base misaligned by 3 floats) are
// staged in LDS transposed+padded, then written with fully coalesced
// scalar stores.
__global__ __launch_bounds__(BLK) void fp4_kernel(
    const float* __restrict__ x,
    const float* __restrict__ delta_raw,
    const float* __restrict__ bounds_base,
    const float* __restrict__ values_table,
    float* __restrict__ out, long long N)
{
    const int tid = threadIdx.x;
    const long long gid = (long long)blockIdx.x * BLK + tid;

    __shared__ float s_vals[8];
    __shared__ float s_w[8 * 264];   // [j][t] with pad: stride 264 floats

    if (tid < 8) s_vals[tid] = values_table[tid];

    // shifted bounds (wave-uniform)
    const float delta = delta_raw[0];
    const float ht = 0.5f * tanhf(delta);
    float sb[7];
#pragma unroll
    for (int j = 0; j < 7; ++j) sb[j] = bounds_base[j] + ht;

    __syncthreads();

    const float xi = x[gid];

    // per-32-block amax via half-wave butterfly
    float a = fabsf(xi);
#pragma unroll
    for (int off = 16; off >= 1; off >>= 1)
        a = fmaxf(a, __shfl_xor(a, off, 32));

    const float descale = a / 6.0f;
    const float e = ceilf(fmaxf(log2f(descale), -127.0f));
    const float scale = exp2f(e);      // power of two -> exact
    const float xs = xi / scale;       // exact division
    const float xa = fabsf(xs);

    int ord = 0;
    float p[7];
#pragma unroll
    for (int j = 0; j < 7; ++j) {
        if (xa > sb[j]) ord++;
        p[j] = 1.0f / (1.0f + expf(-((xa - sb[j]) / 0.1f)));
    }

    float w[8];
    w[0] = 1.0f - p[0];
#pragma unroll
    for (int j = 1; j < 7; ++j) w[j] = p[j - 1] - p[j];
    w[7] = p[6];

    float sum = 0.0f;
#pragma unroll
    for (int k = 0; k < 8; ++k) { w[k] = fmaxf(w[k], 0.0f); sum += w[k]; }
    const float inv = 1.0f / (sum + 1e-8f);

    float abs_soft = 0.0f;
#pragma unroll
    for (int k = 0; k < 8; ++k) { w[k] *= inv; abs_soft += w[k] * s_vals[k]; }

    const float abs_hard = s_vals[ord];              // LDS dynamic index, <=8 addrs
    const float abs_mix = abs_soft + (abs_hard - abs_soft);  // faithful ST expr
    const float ys = (xs >= 0.0f) ? abs_mix : -abs_mix;

    // y
    out[gid] = ys * scale;
    // codes
    const int code = ((xs < 0.0f) ? 8 : 0) | ord;
    out[N + gid] = (float)code;
    // scales (one per 32-block)
    if ((tid & 31) == 0) out[2 * N + (gid >> 5)] = e + 127.0f;
    // shifted_bounds (7 floats, once)
    if (blockIdx.x == 0 && tid < 7) out[2 * N + (N >> 5) + tid] = sb[tid];

    // stage normalized weights transposed: write stride-1 per j (conflict-free)
#pragma unroll
    for (int j = 0; j < 8; ++j) s_w[j * 264 + tid] = w[j];
    __syncthreads();

    // coalesced writeback: linear pos g in [0,2048) maps to elem g>>3, weight g&7
    const long long wbase = 2 * N + (N >> 5) + 7 + (long long)blockIdx.x * (BLK * 8);
#pragma unroll
    for (int k = 0; k < 8; ++k) {
        const int g = tid + k * BLK;
        out[wbase + g] = s_w[(g & 7) * 264 + (g >> 3)];  // 2 lanes/bank -> free
    }
}

extern "C" void kernel_launch(void* const* d_in, const int* in_sizes, int n_in,
                              void* d_out, int out_size, void* d_ws, size_t ws_size,
                              hipStream_t stream) {
    const float* x      = (const float*)d_in[0];
    const float* delta  = (const float*)d_in[1];
    const float* bounds = (const float*)d_in[2];
    const float* vals   = (const float*)d_in[3];
    float* out = (float*)d_out;
    const long long N = (long long)in_sizes[0];   // 8388608, divisible by 256
    const int nblocks = (int)(N / BLK);
    fp4_kernel<<<nblocks, BLK, 0, stream>>>(x, delta, bounds, vals, out, N);
}